// Round 1
// baseline (217.697 us; speedup 1.0000x reference)
//
#include <hip/hip_runtime.h>

#define N_BATCH   50000
#define N_FEATURE 128
#define DEPTH     9
#define N_TREE    200
#define N_NODE    1023
#define N_OUTPUT  8

// Block shape: 64 batches/block (x rows in LDS = 32KB -> 5 blocks/CU),
// 4 tree-groups within the block (4 threads share a batch), grid-level
// tree split TG=5 -> 10 trees per thread, grid = 782*5 = 3910 blocks.
#define BPB    64
#define GROUPS 4
#define TG     5
#define TREES_PER_THREAD (N_TREE / (GROUPS * TG))   // 10
#define BLOCK  (BPB * GROUPS)                        // 256
#define NCHUNK ((N_BATCH + BPB - 1) / BPB)           // 782

__global__ __launch_bounds__(BLOCK, 5)
void tree_ensemble_kernel(const float* __restrict__ x,
                          const int*   __restrict__ feature,
                          const float* __restrict__ threshold,
                          const float* __restrict__ value,
                          float*       __restrict__ out)
{
    __shared__ float xs[BPB * N_FEATURE];   // 32 KB: x rows for this chunk

    const int tid     = threadIdx.x;
    const int work    = blockIdx.x;
    const int chunk   = work / TG;     // which 64-batch chunk
    const int tg      = work % TG;     // which 40-tree slice
    const int b_local = tid & 63;      // wave = one tree-group, 64 batches
    const int g       = tid >> 6;      // tree-group within block

    const int b_global = chunk * BPB + b_local;
    const bool valid   = (b_global < N_BATCH);

    // ---- stage this chunk's x rows into LDS (coalesced float4) ----
    {
        const float4* x4 = (const float4*)x;
        float4* xs4 = (float4*)xs;
        const int base4  = chunk * (BPB * N_FEATURE / 4);   // 2048 float4/chunk
        const int total4 = (N_BATCH * N_FEATURE) / 4;
        #pragma unroll
        for (int k = 0; k < (BPB * N_FEATURE / 4) / BLOCK; ++k) {  // 8 iters
            const int j  = tid + k * BLOCK;
            const int gi = base4 + j;
            if (gi < total4) xs4[j] = x4[gi];
        }
    }
    __syncthreads();

    float acc[N_OUTPUT] = {0.f, 0.f, 0.f, 0.f, 0.f, 0.f, 0.f, 0.f};

    if (valid) {
        const float* xrow = xs + b_local * N_FEATURE;
        const int tree0 = (tg * GROUPS + g) * TREES_PER_THREAD;

        // two trees in flight for ILP (traversal chain is serially dependent)
        for (int i = 0; i < TREES_PER_THREAD; i += 2) {
            const int baseA = (tree0 + i)     * N_NODE;
            const int baseB = (tree0 + i + 1) * N_NODE;
            int nA = 0, nB = 0;
            #pragma unroll
            for (int d = 0; d < DEPTH; ++d) {
                const int   fA  = feature[baseA + nA];
                const int   fB  = feature[baseB + nB];
                const float thA = threshold[baseA + nA];
                const float thB = threshold[baseB + nB];
                const float xvA = xrow[fA];
                const float xvB = xrow[fB];
                // reference: xval <= split -> left(2n+1) else right(2n+2)
                nA = 2 * nA + 1 + (xvA > thA ? 1 : 0);
                nB = 2 * nB + 1 + (xvB > thB ? 1 : 0);
            }
            const float4* vA = (const float4*)(value + (size_t)(baseA + nA) * N_OUTPUT);
            const float4* vB = (const float4*)(value + (size_t)(baseB + nB) * N_OUTPUT);
            const float4 a0 = vA[0], a1 = vA[1];
            const float4 b0 = vB[0], b1 = vB[1];
            acc[0] += a0.x + b0.x;  acc[1] += a0.y + b0.y;
            acc[2] += a0.z + b0.z;  acc[3] += a0.w + b0.w;
            acc[4] += a1.x + b1.x;  acc[5] += a1.y + b1.y;
            acc[6] += a1.z + b1.z;  acc[7] += a1.w + b1.w;
        }
    }

    // ---- reduce the 4 tree-groups within the block (reuse xs LDS) ----
    __syncthreads();   // traversal done; xs no longer needed
    float* red = xs;   // [GROUPS][BPB][N_OUTPUT] = 8 KB
    {
        float* dst = red + ((size_t)(g * BPB + b_local) * N_OUTPUT);
        #pragma unroll
        for (int o = 0; o < N_OUTPUT; ++o) dst[o] = acc[o];
    }
    __syncthreads();

    if (tid < BPB) {
        const int bg = chunk * BPB + tid;
        if (bg < N_BATCH) {
            #pragma unroll
            for (int o = 0; o < N_OUTPUT; ++o) {
                float s = red[(0 * BPB + tid) * N_OUTPUT + o]
                        + red[(1 * BPB + tid) * N_OUTPUT + o]
                        + red[(2 * BPB + tid) * N_OUTPUT + o]
                        + red[(3 * BPB + tid) * N_OUTPUT + o];
                atomicAdd(out + (size_t)bg * N_OUTPUT + o, s * (1.0f / N_TREE));
            }
        }
    }
}

extern "C" void kernel_launch(void* const* d_in, const int* in_sizes, int n_in,
                              void* d_out, int out_size, void* d_ws, size_t ws_size,
                              hipStream_t stream) {
    const float* x         = (const float*)d_in[0];
    const int*   feature   = (const int*)d_in[1];
    const float* threshold = (const float*)d_in[2];
    // d_in[3]/d_in[4] (children_left/right) are implied by complete-tree layout
    const float* value     = (const float*)d_in[5];
    float* out = (float*)d_out;

    // d_out is poisoned 0xAA before every call — zero it (atomic accumulation)
    hipMemsetAsync(out, 0, (size_t)out_size * sizeof(float), stream);

    dim3 grid(NCHUNK * TG);
    dim3 block(BLOCK);
    tree_ensemble_kernel<<<grid, block, 0, stream>>>(x, feature, threshold, value, out);
}

// Round 2
// 179.624 us; speedup vs baseline: 1.2120x; 1.2120x over previous
//
#include <hip/hip_runtime.h>

#define N_BATCH   50000
#define N_FEATURE 128
#define DEPTH     9
#define N_TREE    200
#define N_NODE    1023
#define N_OUTPUT  8

#define BPB    64                        // batches per block
#define GROUPS 4                         // tree-groups (waves) per block
#define TG     5                         // grid-level tree split
#define TPT    (N_TREE / (GROUPS * TG))  // 10 trees per thread
#define BLOCK  (BPB * GROUPS)            // 256
#define NCHUNK ((N_BATCH + BPB - 1) / BPB)  // 782
#define CPAD   784                       // padded: multiple of 8 so same-chunk blocks share an XCD

__global__ void pack_kernel(const int* __restrict__ feature,
                            const float* __restrict__ threshold,
                            int2* __restrict__ packed, int n) {
    int i = blockIdx.x * 256 + threadIdx.x;
    if (i < n) packed[i] = make_int2(feature[i], __float_as_int(threshold[i]));
}

template<bool PACKED>
__global__ __launch_bounds__(BLOCK, 3)
void tree_kernel(const float* __restrict__ x,
                 const int*   __restrict__ feature,
                 const float* __restrict__ threshold,
                 const int2*  __restrict__ packed,
                 const float* __restrict__ value,
                 float*       __restrict__ out)
{
    // Transposed x tile: xt[f*64 + b].  Gather bank = b%32 = lane%32 -> 2-way (free).
    __shared__ float  xt[N_FEATURE * BPB];   // 32 KB
    __shared__ float4 R[32 * 32];            // 16 KB swizzled staging / reduction scratch

    const int tid   = threadIdx.x;
    const int tg    = blockIdx.x / CPAD;
    const int chunk = blockIdx.x % CPAD;
    if (chunk >= NCHUNK) return;             // uniform per block: safe before barriers

    // ---- stage x chunk into transposed LDS, conflict-free both phases ----
    const float4* x4 = (const float4*)x;     // 32 float4 per row
    #pragma unroll
    for (int r = 0; r < 2; ++r) {            // two half-chunks of 32 rows
        #pragma unroll
        for (int k = 0; k < 4; ++k) {        // phase 1: coalesced global -> swizzled R
            int j  = tid + k * BLOCK;        // 0..1023
            int bl = j >> 5;                 // local row 0..31
            int f4 = j & 31;
            int gb = chunk * BPB + r * 32 + bl;
            float4 v = (gb < N_BATCH) ? x4[(size_t)gb * 32 + f4]
                                      : make_float4(0.f, 0.f, 0.f, 0.f);
            R[bl * 32 + (f4 ^ bl)] = v;      // XOR swizzle: even bank spread
        }
        __syncthreads();
        {                                    // phase 2: R -> transposed xt
            int b32 = tid & 31;
            int fc  = tid >> 5;              // 0..7
            int b   = r * 32 + b32;
            #pragma unroll
            for (int c = 0; c < 4; ++c) {
                int f4 = fc * 4 + c;
                float4 v = R[b32 * 32 + (f4 ^ b32)];   // perm over lanes: even banks
                xt[(f4 * 4 + 0) * BPB + b] = v.x;      // bank = b%32 = lane%32: free
                xt[(f4 * 4 + 1) * BPB + b] = v.y;
                xt[(f4 * 4 + 2) * BPB + b] = v.z;
                xt[(f4 * 4 + 3) * BPB + b] = v.w;
            }
        }
        __syncthreads();
    }

    // ---- traversal: 5 trees in flight per thread for MLP ----
    float acc[N_OUTPUT];
    #pragma unroll
    for (int o = 0; o < N_OUTPUT; ++o) acc[o] = 0.f;

    const int b_local = tid & 63;
    const int g       = tid >> 6;
    const int tree0   = (tg * GROUPS + g) * TPT;

    #pragma unroll
    for (int io = 0; io < 2; ++io) {
        int base[5], n[5];
        #pragma unroll
        for (int u = 0; u < 5; ++u) { base[u] = (tree0 + io * 5 + u) * N_NODE; n[u] = 0; }
        #pragma unroll
        for (int d = 0; d < DEPTH; ++d) {
            #pragma unroll
            for (int u = 0; u < 5; ++u) {
                int f; float th;
                if (PACKED) {
                    int2 rec = packed[base[u] + n[u]];
                    f = rec.x; th = __int_as_float(rec.y);
                } else {
                    f  = feature[base[u] + n[u]];
                    th = threshold[base[u] + n[u]];
                }
                float xv = xt[f * BPB + b_local];
                // reference: xval <= split -> left (2n+1), else right (2n+2)
                n[u] = 2 * n[u] + 1 + (xv > th ? 1 : 0);
            }
        }
        #pragma unroll
        for (int u = 0; u < 5; ++u) {
            const float4* vp = (const float4*)(value + (size_t)(base[u] + n[u]) * N_OUTPUT);
            float4 a0 = vp[0], a1 = vp[1];
            acc[0] += a0.x; acc[1] += a0.y; acc[2] += a0.z; acc[3] += a0.w;
            acc[4] += a1.x; acc[5] += a1.y; acc[6] += a1.z; acc[7] += a1.w;
        }
    }

    // ---- in-block reduction over the 4 groups (reuse R's memory) ----
    float* red = (float*)R;                  // [GROUPS][BPB][N_OUTPUT] = 8 KB
    {
        float* dst = red + (size_t)(g * BPB + b_local) * N_OUTPUT;
        #pragma unroll
        for (int o = 0; o < N_OUTPUT; ++o) dst[o] = acc[o];
    }
    __syncthreads();

    if (tid < BPB) {
        const int bg = chunk * BPB + tid;
        if (bg < N_BATCH) {
            #pragma unroll
            for (int o = 0; o < N_OUTPUT; ++o) {
                float s = red[(0 * BPB + tid) * N_OUTPUT + o]
                        + red[(1 * BPB + tid) * N_OUTPUT + o]
                        + red[(2 * BPB + tid) * N_OUTPUT + o]
                        + red[(3 * BPB + tid) * N_OUTPUT + o];
                atomicAdd(out + (size_t)bg * N_OUTPUT + o, s * (1.0f / N_TREE));
            }
        }
    }
}

extern "C" void kernel_launch(void* const* d_in, const int* in_sizes, int n_in,
                              void* d_out, int out_size, void* d_ws, size_t ws_size,
                              hipStream_t stream) {
    const float* x         = (const float*)d_in[0];
    const int*   feature   = (const int*)d_in[1];
    const float* threshold = (const float*)d_in[2];
    const float* value     = (const float*)d_in[5];   // children implied by complete tree
    float* out = (float*)d_out;

    hipMemsetAsync(out, 0, (size_t)out_size * sizeof(float), stream);

    const size_t packed_bytes = (size_t)N_TREE * N_NODE * sizeof(int2);  // 1.64 MB
    dim3 grid(TG * CPAD);    // 3920; bid = tg*784 + chunk -> same-chunk blocks same XCD
    dim3 block(BLOCK);

    if (ws_size >= packed_bytes) {
        int2* packed = (int2*)d_ws;
        const int n = N_TREE * N_NODE;
        pack_kernel<<<(n + 255) / 256, 256, 0, stream>>>(feature, threshold, packed, n);
        tree_kernel<true><<<grid, block, 0, stream>>>(x, feature, threshold, packed, value, out);
    } else {
        tree_kernel<false><<<grid, block, 0, stream>>>(x, feature, threshold, nullptr, value, out);
    }
}

// Round 3
// 177.889 us; speedup vs baseline: 1.2238x; 1.0098x over previous
//
#include <hip/hip_runtime.h>

#define N_BATCH   50000
#define N_FEATURE 128
#define DEPTH     9
#define N_TREE    200
#define N_NODE    1023
#define N_OUTPUT  8

#define BPB     64                            // batches per block
#define BLOCK   256                           // 4 waves
#define NCHUNK  ((N_BATCH + BPB - 1) / BPB)   // 782 blocks (768 resident at 3/CU)
#define TPR     8                             // trees per round (2 per wave -> ILP 2)
#define ROUNDS  (N_TREE / TPR)                // 25
#define SLOTS   (TPR * 512)                   // 4096 staged records per round
#define SPT     (SLOTS / BLOCK)               // 16 slots per thread

// LDS: xt 32KB + scratch 16KB (thS / transpose-R / reduction) + fS 4KB = 52KB
// -> 3 blocks/CU (156KB of 160KB), 12 waves/CU.
__global__ __launch_bounds__(BLOCK, 3)
void tree_kernel(const float* __restrict__ x,
                 const int*   __restrict__ feature,
                 const float* __restrict__ threshold,
                 const float* __restrict__ value,
                 float*       __restrict__ out)
{
    __shared__ float         xt[N_FEATURE * BPB];   // transposed x: xt[f*64+b], gather bank = b%32 (free)
    __shared__ float         scratch[TPR * 512];    // 16KB: thS, aliased by transpose-R and reduction
    __shared__ unsigned char fS[TPR * 512];         // 4KB: u8 features (internal nodes only, 0..127)

    const int tid   = threadIdx.x;
    const int chunk = blockIdx.x;
    const int b     = tid & 63;    // lane = batch within chunk
    const int g     = tid >> 6;    // wave id: handles trees {2g, 2g+1} of each round

    // ---- issue round-0 record prefetch early (in flight during transpose) ----
    float thr[SPT];
    int   fr[SPT];
    #pragma unroll
    for (int j = 0; j < SPT; ++j) {
        const int slot = tid + j * BLOCK;
        const int t = slot >> 9, n = slot & 511;     // n=511 staged but never read
        const int gi = t * N_NODE + n;
        thr[j] = threshold[gi];
        fr[j]  = feature[gi];
    }

    // ---- stage x chunk transposed into LDS (conflict-free, via swizzled R) ----
    {
        const float4* x4 = (const float4*)x;         // 32 float4 per row
        float4* R = (float4*)scratch;                // 32x32 float4 = 16KB
        #pragma unroll
        for (int rr = 0; rr < 2; ++rr) {             // two half-chunks of 32 rows
            #pragma unroll
            for (int k = 0; k < 4; ++k) {            // coalesced global -> swizzled R
                const int j  = tid + k * BLOCK;      // 0..1023
                const int bl = j >> 5, f4 = j & 31;
                const int gb = chunk * BPB + rr * 32 + bl;
                float4 v = (gb < N_BATCH) ? x4[(size_t)gb * 32 + f4]
                                          : make_float4(0.f, 0.f, 0.f, 0.f);
                R[bl * 32 + (f4 ^ bl)] = v;
            }
            __syncthreads();
            {
                const int b32 = tid & 31, fc = tid >> 5;
                const int bb = rr * 32 + b32;
                #pragma unroll
                for (int c = 0; c < 4; ++c) {
                    const int f4 = fc * 4 + c;
                    float4 v = R[b32 * 32 + (f4 ^ b32)];
                    xt[(f4 * 4 + 0) * BPB + bb] = v.x;
                    xt[(f4 * 4 + 1) * BPB + bb] = v.y;
                    xt[(f4 * 4 + 2) * BPB + bb] = v.z;
                    xt[(f4 * 4 + 3) * BPB + bb] = v.w;
                }
            }
            __syncthreads();
        }
    }

    float acc[N_OUTPUT];
    #pragma unroll
    for (int o = 0; o < N_OUTPUT; ++o) acc[o] = 0.f;

    float* thS = scratch;
    const int tl0 = 2 * g, tl1 = 2 * g + 1;

    for (int r = 0; r < ROUNDS; ++r) {
        __syncthreads();                      // stage buffer free (prev round read done)
        #pragma unroll
        for (int j = 0; j < SPT; ++j) {       // regs -> LDS stage
            const int slot = tid + j * BLOCK;
            thS[slot] = thr[j];
            fS[slot]  = (unsigned char)fr[j];
        }
        __syncthreads();                      // stage ready

        if (r + 1 < ROUNDS) {                 // prefetch next round into registers
            #pragma unroll
            for (int j = 0; j < SPT; ++j) {
                const int slot = tid + j * BLOCK;
                const int t = slot >> 9, n = slot & 511;
                const int gi = ((r + 1) * TPR + t) * N_NODE + n;
                thr[j] = threshold[gi];
                fr[j]  = feature[gi];
            }
        }

        // ---- traverse 2 trees (ILP 2), all-LDS step chain ----
        int n0 = 0, n1 = 0;
        #pragma unroll
        for (int d = 0; d < DEPTH; ++d) {
            const int   f0 = fS[tl0 * 512 + n0];
            const int   f1 = fS[tl1 * 512 + n1];
            const float t0 = thS[tl0 * 512 + n0];
            const float t1 = thS[tl1 * 512 + n1];
            const float x0 = xt[f0 * BPB + b];
            const float x1 = xt[f1 * BPB + b];
            n0 = 2 * n0 + 1 + (x0 > t0 ? 1 : 0);   // xval <= split -> left
            n1 = 2 * n1 + 1 + (x1 > t1 ? 1 : 0);
        }

        const int gt0 = r * TPR + tl0;
        const int gt1 = r * TPR + tl1;
        const float4* v0 = (const float4*)(value + ((size_t)gt0 * N_NODE + n0) * N_OUTPUT);
        const float4* v1 = (const float4*)(value + ((size_t)gt1 * N_NODE + n1) * N_OUTPUT);
        const float4 a0 = v0[0], a1 = v0[1];
        const float4 c0 = v1[0], c1 = v1[1];
        acc[0] += a0.x + c0.x;  acc[1] += a0.y + c0.y;
        acc[2] += a0.z + c0.z;  acc[3] += a0.w + c0.w;
        acc[4] += a1.x + c1.x;  acc[5] += a1.y + c1.y;
        acc[6] += a1.z + c1.z;  acc[7] += a1.w + c1.w;
    }

    // ---- reduce 4 waves' partials (reuse scratch, stride-9 pad) ----
    __syncthreads();
    float* red = scratch;                     // 4*576 floats = 9216B <= 16KB
    {
        float* dst = red + (g * 576 + b * 9);
        #pragma unroll
        for (int o = 0; o < N_OUTPUT; ++o) dst[o] = acc[o];
    }
    __syncthreads();
    {
        const int bl = tid >> 2;              // batch 0..63
        const int o0 = (tid & 3) * 2;         // output pair
        const int bg = chunk * BPB + bl;
        if (bg < N_BATCH) {
            float s0 = 0.f, s1 = 0.f;
            #pragma unroll
            for (int gg = 0; gg < 4; ++gg) {
                s0 += red[gg * 576 + bl * 9 + o0];
                s1 += red[gg * 576 + bl * 9 + o0 + 1];
            }
            float2 res;
            res.x = s0 * (1.0f / N_TREE);
            res.y = s1 * (1.0f / N_TREE);
            ((float2*)out)[(size_t)chunk * 256 + tid] = res;   // coalesced, exactly once
        }
    }
}

extern "C" void kernel_launch(void* const* d_in, const int* in_sizes, int n_in,
                              void* d_out, int out_size, void* d_ws, size_t ws_size,
                              hipStream_t stream) {
    const float* x         = (const float*)d_in[0];
    const int*   feature   = (const int*)d_in[1];
    const float* threshold = (const float*)d_in[2];
    const float* value     = (const float*)d_in[5];   // children implied by complete heap layout
    float* out = (float*)d_out;

    // single launch: every out element written exactly once (no memset, no atomics)
    tree_kernel<<<dim3(NCHUNK), dim3(BLOCK), 0, stream>>>(x, feature, threshold, value, out);
}